// Round 1
// baseline (263.340 us; speedup 1.0000x reference)
//
#include <hip/hip_runtime.h>
#include <math.h>

#define NN 1024
#define IN_DIM 64
#define H 128
#define NL 4
#define HEADS 4
#define DH 32

// ---------------- transpose in_proj_W [384,128] -> [128,384], out_proj_W [128,128] -> [128,128]T
__global__ void k_transpose(const float* __restrict__ inW, const float* __restrict__ outW,
                            float* __restrict__ Wt_in, float* __restrict__ Wt_out) {
    int idx = blockIdx.x * blockDim.x + threadIdx.x;
    if (idx < 384 * 128) {
        int k = idx / 384, m = idx % 384;
        Wt_in[idx] = inW[m * 128 + k];
    }
    int idx2 = idx - 384 * 128;
    if (idx2 >= 0 && idx2 < 128 * 128) {
        int k = idx2 / 128, c = idx2 % 128;
        Wt_out[idx2] = outW[c * 128 + k];
    }
}

// ---------------- embed: h = relu(LN(x@embW+b)) ; a = h@W1a + eb1 ; bmat = h@W1b
__global__ __launch_bounds__(128) void k_embed(const float* __restrict__ x,
        const float* __restrict__ embW, const float* __restrict__ embB,
        const float* __restrict__ lng, const float* __restrict__ lnb,
        const float* __restrict__ eW1, const float* __restrict__ eb1,
        float* __restrict__ h0, float* __restrict__ aM, float* __restrict__ bM) {
    __shared__ float xs[IN_DIM];
    __shared__ float hs[H];
    __shared__ float red[H];
    int i = blockIdx.x, t = threadIdx.x;
    if (t < IN_DIM) xs[t] = x[i * IN_DIM + t];
    __syncthreads();
    float acc = embB[t];
    #pragma unroll 8
    for (int k = 0; k < IN_DIM; ++k) acc = fmaf(xs[k], embW[k * H + t], acc);
    red[t] = acc; __syncthreads();
    for (int s = 64; s > 0; s >>= 1) { if (t < s) red[t] += red[t + s]; __syncthreads(); }
    float mu = red[0] * (1.f / H);
    __syncthreads();
    float d = acc - mu;
    red[t] = d * d; __syncthreads();
    for (int s = 64; s > 0; s >>= 1) { if (t < s) red[t] += red[t + s]; __syncthreads(); }
    float var = red[0] * (1.f / H);
    float hv = d * rsqrtf(var + 1e-5f) * lng[t] + lnb[t];
    hv = fmaxf(hv, 0.f);
    hs[t] = hv;
    h0[i * H + t] = hv;
    __syncthreads();
    float aa = eb1[t], bb = 0.f;
    #pragma unroll 8
    for (int k = 0; k < H; ++k) {
        float hk = hs[k];
        aa = fmaf(hk, eW1[k * H + t], aa);
        bb = fmaf(hk, eW1[(H + k) * H + t], bb);
    }
    aM[i * H + t] = aa;
    bM[i * H + t] = bb;
}

// ---------------- adj[i][j] = sigmoid( sum_h relu(a_i[h]+b_j[h]) * w2[h] + eb2 ), diag 0
#define BT 16
__global__ __launch_bounds__(256) void k_adj(const float* __restrict__ aM, const float* __restrict__ bM,
        const float* __restrict__ w2, const float* __restrict__ eb2p, float* __restrict__ adj) {
    __shared__ float as_[BT][H + 1];
    __shared__ float bs_[BT][H + 1];
    __shared__ float w2s[H];
    int i0 = blockIdx.y * BT, j0 = blockIdx.x * BT;
    int t = threadIdx.x;
    for (int idx = t; idx < BT * H; idx += 256) {
        int r = idx / H, c = idx % H;
        as_[r][c] = aM[(i0 + r) * H + c];
        bs_[r][c] = bM[(j0 + r) * H + c];
    }
    if (t < H) w2s[t] = w2[t];
    __syncthreads();
    int ti = t / BT, tj = t % BT;
    float acc = 0.f;
    #pragma unroll 4
    for (int h = 0; h < H; ++h) {
        float e = fmaxf(as_[ti][h] + bs_[tj][h], 0.f);
        acc = fmaf(e, w2s[h], acc);
    }
    acc += eb2p[0];
    float sig = 1.f / (1.f + expf(-acc));
    int i = i0 + ti, j = j0 + tj;
    adj[i * NN + j] = (i == j) ? 0.f : sig;
}

// ---------------- generic row-parallel matmul: out[i][c] = sum_k in[i][k]*W[k*C+c] (+bias[c])
__global__ void k_rowmat(const float* __restrict__ inM, const float* __restrict__ W,
        const float* __restrict__ bias, float* __restrict__ outM, int K, int C) {
    extern __shared__ float rs[];
    int i = blockIdx.x, t = threadIdx.x;
    for (int k = t; k < K; k += blockDim.x) rs[k] = inM[i * K + k];
    __syncthreads();
    float acc = bias ? bias[t] : 0.f;
    #pragma unroll 8
    for (int k = 0; k < K; ++k) acc = fmaf(rs[k], W[k * C + t], acc);
    outM[i * C + t] = acc;
}

// ---------------- partial[p][i][c] = sum_{j in chunk p} adj[i][j]*g[j][c]
#define RT 4
#define JC 256
__global__ __launch_bounds__(256) void k_spmm(const float* __restrict__ adj, const float* __restrict__ g,
        float* __restrict__ partial) {
    __shared__ float adjs[RT][JC];
    int rt = blockIdx.x;   // 0..255
    int p = blockIdx.y;    // 0..3
    int t = threadIdx.x;
    int c = t & 127, rg = t >> 7;
    int r0 = rt * RT;
    int j0 = p * JC;
    for (int idx = t; idx < RT * JC; idx += 256) {
        int r = idx / JC, j = idx % JC;
        adjs[r][j] = adj[(size_t)(r0 + r) * NN + j0 + j];
    }
    __syncthreads();
    float acc0 = 0.f, acc1 = 0.f;
    int ra = rg * 2, rb = rg * 2 + 1;
    #pragma unroll 4
    for (int jj = 0; jj < JC; ++jj) {
        float gv = g[(j0 + jj) * H + c];
        acc0 = fmaf(adjs[ra][jj], gv, acc0);
        acc1 = fmaf(adjs[rb][jj], gv, acc1);
    }
    partial[((size_t)p * NN + r0 + ra) * H + c] = acc0;
    partial[((size_t)p * NN + r0 + rb) * H + c] = acc1;
}

__global__ void k_red4(const float* __restrict__ partial, const float* __restrict__ bias,
        float* __restrict__ outM) {
    int idx = blockIdx.x * blockDim.x + threadIdx.x; // over NN*H
    int c = idx & 127;
    float s = partial[idx] + partial[NN * H + idx] + partial[2 * NN * H + idx] + partial[3 * NN * H + idx];
    outM[idx] = s + bias[c];
}

// ---------------- flash attention: 8 q-rows per block, 4 heads
#define QR 8
#define KC 128
__global__ __launch_bounds__(256) void k_attn(const float* __restrict__ qkv, float* __restrict__ attn_o) {
    __shared__ float qs[QR][DH + 1];
    __shared__ float ks[KC][DH + 1];
    __shared__ float vs[KC][DH + 1];
    __shared__ float ss[QR][KC + 4];
    __shared__ float mrun[QR], lrun[QR], fac[QR];
    int head = blockIdx.y;
    int i0 = blockIdx.x * QR;
    int t = threadIdx.x;
    int koff = head * DH;
    for (int idx = t; idx < QR * DH; idx += 256) {
        int r = idx / DH, d = idx % DH;
        qs[r][d] = qkv[(i0 + r) * 384 + koff + d];
    }
    if (t < QR) { mrun[t] = -1e30f; lrun[t] = 0.f; }
    int r_ = t >> 5, d_ = t & 31;
    float oacc = 0.f;
    const float scale = 0.17677669529663687f; // 1/sqrt(32)
    __syncthreads();
    for (int j0 = 0; j0 < NN; j0 += KC) {
        for (int idx = t; idx < KC * DH; idx += 256) {
            int r = idx / DH, d = idx % DH;
            ks[r][d] = qkv[(j0 + r) * 384 + 128 + koff + d];
            vs[r][d] = qkv[(j0 + r) * 384 + 256 + koff + d];
        }
        __syncthreads();
        {
            int jj = t & 127, half = t >> 7;
            float sc0 = 0, sc1 = 0, sc2 = 0, sc3 = 0;
            int rbase = half * 4;
            #pragma unroll
            for (int kk = 0; kk < DH; ++kk) {
                float kv = ks[jj][kk];
                sc0 = fmaf(qs[rbase + 0][kk], kv, sc0);
                sc1 = fmaf(qs[rbase + 1][kk], kv, sc1);
                sc2 = fmaf(qs[rbase + 2][kk], kv, sc2);
                sc3 = fmaf(qs[rbase + 3][kk], kv, sc3);
            }
            ss[rbase + 0][jj] = sc0 * scale;
            ss[rbase + 1][jj] = sc1 * scale;
            ss[rbase + 2][jj] = sc2 * scale;
            ss[rbase + 3][jj] = sc3 * scale;
        }
        __syncthreads();
        {
            float lm = -1e30f;
            float sv[4];
            #pragma unroll
            for (int k = 0; k < 4; ++k) {
                sv[k] = ss[r_][d_ + 32 * k];
                lm = fmaxf(lm, sv[k]);
            }
            #pragma unroll
            for (int off = 16; off > 0; off >>= 1)
                lm = fmaxf(lm, __shfl_xor(lm, off, 32));
            float mold = mrun[r_];
            float mnew = fmaxf(mold, lm);
            float f = expf(mold - mnew);
            float ls = 0.f;
            #pragma unroll
            for (int k = 0; k < 4; ++k) {
                float p = expf(sv[k] - mnew);
                ss[r_][d_ + 32 * k] = p;
                ls += p;
            }
            #pragma unroll
            for (int off = 16; off > 0; off >>= 1)
                ls += __shfl_xor(ls, off, 32);
            if (d_ == 0) {
                lrun[r_] = lrun[r_] * f + ls;
                mrun[r_] = mnew;
                fac[r_] = f;
            }
        }
        __syncthreads();
        oacc *= fac[r_];
        #pragma unroll 4
        for (int j = 0; j < KC; ++j) {
            oacc = fmaf(ss[r_][j], vs[j][d_], oacc);
        }
        __syncthreads();
    }
    float o = oacc / lrun[r_];
    attn_o[(i0 + r_) * H + koff + d_] = o;
}

// ---------------- pooling + head
__global__ void k_pool1(const float* __restrict__ h2, float* __restrict__ pp) {
    int b = blockIdx.x; // 0..31
    int t = threadIdx.x;
    int c = t & 127, rg = t >> 7;
    int r0 = b * 32 + rg * 16;
    float s = 0.f;
    #pragma unroll
    for (int r = 0; r < 16; ++r) s += h2[(r0 + r) * H + c];
    pp[(b * 2 + rg) * H + c] = s;
}

__global__ void k_pool2(const float* __restrict__ pp, const float* __restrict__ outW,
        const float* __restrict__ outB, float* __restrict__ out) {
    __shared__ float pooled[H];
    int t = threadIdx.x;
    float s = 0.f;
    #pragma unroll 8
    for (int p = 0; p < 64; ++p) s += pp[p * H + t];
    pooled[t] = s * (1.f / 1024.f);
    __syncthreads();
    if (t < 6) {
        float acc = outB[t];
        for (int c = 0; c < H; ++c) acc = fmaf(pooled[c], outW[c * 6 + t], acc);
        out[t] = (t == 1) ? fmaxf(acc, 0.f) : 1.f / (1.f + expf(-acc));
    }
}

extern "C" void kernel_launch(void* const* d_in, const int* in_sizes, int n_in,
                              void* d_out, int out_size, void* d_ws, size_t ws_size,
                              hipStream_t stream) {
    const float* x       = (const float*)d_in[0];
    const float* emb_W   = (const float*)d_in[1];
    const float* emb_b   = (const float*)d_in[2];
    const float* ln_g    = (const float*)d_in[3];
    const float* ln_b    = (const float*)d_in[4];
    const float* edge_W1 = (const float*)d_in[5];
    const float* edge_b1 = (const float*)d_in[6];
    const float* edge_W2 = (const float*)d_in[7];
    const float* edge_b2 = (const float*)d_in[8];
    const float* gc_W    = (const float*)d_in[9];
    const float* gc_b    = (const float*)d_in[10];
    const float* in_proj_W  = (const float*)d_in[11];
    const float* in_proj_b  = (const float*)d_in[12];
    const float* out_proj_W = (const float*)d_in[13];
    const float* out_proj_b = (const float*)d_in[14];
    const float* out_W   = (const float*)d_in[15];
    const float* out_b   = (const float*)d_in[16];
    float* out = (float*)d_out;

    float* ws = (float*)d_ws;
    float* h0      = ws;                 // 1024*128
    float* h1      = h0 + NN * H;        // 1024*128
    float* aM      = h1 + NN * H;        // 1024*128
    float* bM      = aM + NN * H;        // 1024*128
    float* adj     = bM + NN * H;        // 1024*1024
    float* g       = adj + NN * NN;      // 1024*128
    float* qkv     = g + NN * H;         // 1024*384
    float* Wt_in   = qkv + NN * 384;     // 128*384
    float* Wt_out  = Wt_in + 128 * 384;  // 128*128
    float* attn_o  = Wt_out + 128 * 128; // 1024*128
    float* partial = attn_o + NN * H;    // 4*1024*128
    float* h2      = partial + 4 * NN * H; // 1024*128
    float* pp      = h2 + NN * H;        // 64*128

    k_transpose<<<256, 256, 0, stream>>>(in_proj_W, out_proj_W, Wt_in, Wt_out);
    k_embed<<<NN, 128, 0, stream>>>(x, emb_W, emb_b, ln_g, ln_b, edge_W1, edge_b1, h0, aM, bM);
    k_adj<<<dim3(NN / BT, NN / BT), 256, 0, stream>>>(aM, bM, edge_W2, edge_b2, adj);

    float* hc = h0;
    float* hn = h1;
    for (int l = 0; l < NL; ++l) {
        k_rowmat<<<NN, H, H * sizeof(float), stream>>>(hc, gc_W + (size_t)l * H * H, nullptr, g, H, H);
        k_spmm<<<dim3(NN / RT, 4), 256, 0, stream>>>(adj, g, partial);
        k_red4<<<NN * H / 256, 256, 0, stream>>>(partial, gc_b + (size_t)l * H, hn);
        float* tmp = hc; hc = hn; hn = tmp;
    }

    k_rowmat<<<NN, 384, H * sizeof(float), stream>>>(hc, Wt_in, in_proj_b, qkv, H, 384);
    k_attn<<<dim3(NN / QR, HEADS), 256, 0, stream>>>(qkv, attn_o);
    k_rowmat<<<NN, H, H * sizeof(float), stream>>>(attn_o, Wt_out, out_proj_b, h2, H, 128);
    k_pool1<<<32, 256, 0, stream>>>(h2, pp);
    k_pool2<<<1, 128, 0, stream>>>(pp, out_W, out_b, out);
}

// Round 2
// 164.148 us; speedup vs baseline: 1.6043x; 1.6043x over previous
//
#include <hip/hip_runtime.h>
#include <math.h>

#define NN 1024
#define IN_DIM 64
#define H 128
#define NL 4
#define HEADS 4
#define DH 32

// ---------------- transpose in_proj_W [384,128] -> [128,384], out_proj_W [128,128] -> T
__global__ void k_transpose(const float* __restrict__ inW, const float* __restrict__ outW,
                            float* __restrict__ Wt_in, float* __restrict__ Wt_out) {
    int idx = blockIdx.x * blockDim.x + threadIdx.x;
    if (idx < 384 * 128) {
        int k = idx / 384, m = idx % 384;
        Wt_in[idx] = inW[m * 128 + k];
    }
    int idx2 = idx - 384 * 128;
    if (idx2 >= 0 && idx2 < 128 * 128) {
        int k = idx2 / 128, c = idx2 % 128;
        Wt_out[idx2] = outW[c * 128 + k];
    }
}

// ---------------- embed: h=relu(LN(x@embW+b)); aM=h@W1a+eb1; bM=h@W1b; g0=h@gcW0
__global__ __launch_bounds__(128) void k_embed(const float* __restrict__ x,
        const float* __restrict__ embW, const float* __restrict__ embB,
        const float* __restrict__ lng, const float* __restrict__ lnb,
        const float* __restrict__ eW1, const float* __restrict__ eb1,
        const float* __restrict__ gcW0,
        float* __restrict__ aM, float* __restrict__ bM, float* __restrict__ g0) {
    __shared__ float xs[IN_DIM];
    __shared__ float hs[H];
    __shared__ float red[H];
    int i = blockIdx.x, t = threadIdx.x;
    if (t < IN_DIM) xs[t] = x[i * IN_DIM + t];
    __syncthreads();
    float acc = embB[t];
    #pragma unroll 8
    for (int k = 0; k < IN_DIM; ++k) acc = fmaf(xs[k], embW[k * H + t], acc);
    red[t] = acc; __syncthreads();
    for (int s = 64; s > 0; s >>= 1) { if (t < s) red[t] += red[t + s]; __syncthreads(); }
    float mu = red[0] * (1.f / H);
    __syncthreads();
    float d = acc - mu;
    red[t] = d * d; __syncthreads();
    for (int s = 64; s > 0; s >>= 1) { if (t < s) red[t] += red[t + s]; __syncthreads(); }
    float var = red[0] * (1.f / H);
    float hv = d * rsqrtf(var + 1e-5f) * lng[t] + lnb[t];
    hv = fmaxf(hv, 0.f);
    hs[t] = hv;
    __syncthreads();
    float aa = eb1[t], bb = 0.f, gg = 0.f;
    #pragma unroll 8
    for (int k = 0; k < H; ++k) {
        float hk = hs[k];
        aa = fmaf(hk, eW1[k * H + t], aa);
        bb = fmaf(hk, eW1[(H + k) * H + t], bb);
        gg = fmaf(hk, gcW0[k * H + t], gg);
    }
    aM[i * H + t] = aa;
    bM[i * H + t] = bb;
    g0[i * H + t] = gg;
}

// ---------------- adj: 32x32 tile, b transposed in LDS, 4 outputs/thread via float4
#define AT 32
__global__ __launch_bounds__(256) void k_adj(const float* __restrict__ aM, const float* __restrict__ bM,
        const float* __restrict__ w2, const float* __restrict__ eb2p, float* __restrict__ adj) {
    __shared__ float as_[AT][H + 4];   // stride 132 -> bank step 4 across ti
    __shared__ float bst[H][AT + 4];   // stride 36, 16B-aligned rows
    __shared__ float w2s[H];
    int i0 = blockIdx.y * AT, j0 = blockIdx.x * AT;
    int t = threadIdx.x;
    for (int idx = t; idx < AT * H; idx += 256) {
        int r = idx >> 7, c = idx & 127;
        as_[r][c] = aM[(i0 + r) * H + c];
        bst[c][r] = bM[(j0 + r) * H + c];
    }
    if (t < H) w2s[t] = w2[t];
    __syncthreads();
    int ti = t >> 3, tjg = t & 7;       // 32 rows x 8 col-groups(4)
    float a0 = 0.f, a1 = 0.f, a2 = 0.f, a3 = 0.f;
    const float eb2 = eb2p[0];
    #pragma unroll 4
    for (int h = 0; h < H; ++h) {
        float av = as_[ti][h];
        float4 bv = *(const float4*)&bst[h][tjg * 4];
        float wh = w2s[h];
        a0 = fmaf(fmaxf(av + bv.x, 0.f), wh, a0);
        a1 = fmaf(fmaxf(av + bv.y, 0.f), wh, a1);
        a2 = fmaf(fmaxf(av + bv.z, 0.f), wh, a2);
        a3 = fmaf(fmaxf(av + bv.w, 0.f), wh, a3);
    }
    int i = i0 + ti, jb = j0 + tjg * 4;
    float4 ov;
    ov.x = (i == jb + 0) ? 0.f : 1.f / (1.f + __expf(-(a0 + eb2)));
    ov.y = (i == jb + 1) ? 0.f : 1.f / (1.f + __expf(-(a1 + eb2)));
    ov.z = (i == jb + 2) ? 0.f : 1.f / (1.f + __expf(-(a2 + eb2)));
    ov.w = (i == jb + 3) ? 0.f : 1.f / (1.f + __expf(-(a3 + eb2)));
    *(float4*)&adj[(size_t)i * NN + jb] = ov;
}

// ---------------- generic row matmul (used for out_proj)
__global__ void k_rowmat(const float* __restrict__ inM, const float* __restrict__ W,
        const float* __restrict__ bias, float* __restrict__ outM, int K, int C) {
    extern __shared__ float rs[];
    int i = blockIdx.x, t = threadIdx.x;
    for (int k = t; k < K; k += blockDim.x) rs[k] = inM[i * K + k];
    __syncthreads();
    float acc = bias ? bias[t] : 0.f;
    #pragma unroll 8
    for (int k = 0; k < K; ++k) acc = fmaf(rs[k], W[k * C + t], acc);
    outM[i * C + t] = acc;
}

// ---------------- spmm: partial[p][i][c] = sum_{j in chunk} adj[i][j]*g[j][c]
#define RT 8
#define JC 256
__global__ __launch_bounds__(256) void k_spmm(const float* __restrict__ adj, const float* __restrict__ g,
        float* __restrict__ partial) {
    __shared__ float adjs[RT][JC];          // 8 KB
    __shared__ float redbuf[RT][H];         // 4 KB
    int rt = blockIdx.x;   // 0..127
    int p = blockIdx.y;    // 0..3
    int t = threadIdx.x;
    int c = t & 127, half = t >> 7;
    int r0 = rt * RT;
    for (int idx = t; idx < RT * JC; idx += 256) {
        int r = idx >> 8, j = idx & 255;
        adjs[r][j] = adj[(size_t)(r0 + r) * NN + p * JC + j];
    }
    __syncthreads();
    int jbase = half * 128;
    int j0 = p * JC + jbase;
    float acc[RT];
    #pragma unroll
    for (int r = 0; r < RT; ++r) acc[r] = 0.f;
    #pragma unroll 8
    for (int jj = 0; jj < 128; ++jj) {
        float gv = g[(j0 + jj) * H + c];
        int ja = jbase + jj;
        #pragma unroll
        for (int r = 0; r < RT; ++r) acc[r] = fmaf(adjs[r][ja], gv, acc[r]);
    }
    if (half == 1) {
        #pragma unroll
        for (int r = 0; r < RT; ++r) redbuf[r][c] = acc[r];
    }
    __syncthreads();
    if (half == 0) {
        #pragma unroll
        for (int r = 0; r < RT; ++r)
            partial[((size_t)p * NN + r0 + r) * H + c] = acc[r] + redbuf[r][c];
    }
}

// ---------------- fused 4-way reduce + bias + next matmul
__global__ __launch_bounds__(128) void k_redmat128(const float* __restrict__ partial,
        const float* __restrict__ bias, const float* __restrict__ W, float* __restrict__ outM) {
    __shared__ float s[H];
    int i = blockIdx.x, t = threadIdx.x;
    float v = partial[i * H + t] + partial[NN * H + i * H + t]
            + partial[2 * NN * H + i * H + t] + partial[3 * NN * H + i * H + t] + bias[t];
    s[t] = v;
    __syncthreads();
    float acc = 0.f;
    #pragma unroll 8
    for (int k = 0; k < H; ++k) acc = fmaf(s[k], W[k * H + t], acc);
    outM[i * H + t] = acc;
}

__global__ __launch_bounds__(384) void k_redmat384(const float* __restrict__ partial,
        const float* __restrict__ bias, const float* __restrict__ W,
        const float* __restrict__ bias2, float* __restrict__ outM) {
    __shared__ float s[H];
    int i = blockIdx.x, t = threadIdx.x;
    if (t < H) {
        float v = partial[i * H + t] + partial[NN * H + i * H + t]
                + partial[2 * NN * H + i * H + t] + partial[3 * NN * H + i * H + t] + bias[t];
        s[t] = v;
    }
    __syncthreads();
    float acc = bias2[t];
    #pragma unroll 8
    for (int k = 0; k < H; ++k) acc = fmaf(s[k], W[k * 384 + t], acc);
    outM[i * 384 + t] = acc;
}

// ---------------- split-K attention: one K-chunk per block, no online loop
#define QR 8
#define KC 128
#define KSPLIT 8
__global__ __launch_bounds__(256) void k_attn_part(const float* __restrict__ qkv,
        float* __restrict__ opart, float* __restrict__ mpart, float* __restrict__ lpart) {
    __shared__ float qs[QR][DH + 4];
    __shared__ float ks[KC][DH + 1];
    __shared__ float vs[KC][DH + 1];
    __shared__ float ss[QR][KC + 4];
    int head = blockIdx.y;
    int i0 = blockIdx.x * QR;
    int kp = blockIdx.z;
    int j0 = kp * KC;
    int t = threadIdx.x;
    int qoff = head * DH, koff = 128 + head * DH, voff = 256 + head * DH;
    for (int idx = t; idx < KC * DH; idx += 256) {
        int r = idx >> 5, d = idx & 31;
        ks[r][d] = qkv[(j0 + r) * 384 + koff + d];
        vs[r][d] = qkv[(j0 + r) * 384 + voff + d];
    }
    {
        int r = t >> 5, d = t & 31;   // 256 = QR*DH exactly
        qs[r][d] = qkv[(i0 + r) * 384 + qoff + d];
    }
    __syncthreads();
    const float scale = 0.17677669529663687f; // 1/sqrt(32)
    {
        int jj = t & 127, rb = (t >> 7) * 4;
        float s0 = 0.f, s1 = 0.f, s2 = 0.f, s3 = 0.f;
        #pragma unroll
        for (int kk = 0; kk < DH; ++kk) {
            float kv = ks[jj][kk];
            s0 = fmaf(qs[rb + 0][kk], kv, s0);
            s1 = fmaf(qs[rb + 1][kk], kv, s1);
            s2 = fmaf(qs[rb + 2][kk], kv, s2);
            s3 = fmaf(qs[rb + 3][kk], kv, s3);
        }
        ss[rb + 0][jj] = s0 * scale;
        ss[rb + 1][jj] = s1 * scale;
        ss[rb + 2][jj] = s2 * scale;
        ss[rb + 3][jj] = s3 * scale;
    }
    __syncthreads();
    int r_ = t >> 5, d_ = t & 31;
    float sv0 = ss[r_][d_], sv1 = ss[r_][d_ + 32], sv2 = ss[r_][d_ + 64], sv3 = ss[r_][d_ + 96];
    float m = fmaxf(fmaxf(sv0, sv1), fmaxf(sv2, sv3));
    #pragma unroll
    for (int off = 16; off > 0; off >>= 1) m = fmaxf(m, __shfl_xor(m, off, 32));
    float p0 = __expf(sv0 - m), p1 = __expf(sv1 - m), p2 = __expf(sv2 - m), p3 = __expf(sv3 - m);
    ss[r_][d_] = p0; ss[r_][d_ + 32] = p1; ss[r_][d_ + 64] = p2; ss[r_][d_ + 96] = p3;
    float l = p0 + p1 + p2 + p3;
    #pragma unroll
    for (int off = 16; off > 0; off >>= 1) l += __shfl_xor(l, off, 32);
    // p-values written & read by the same wave (rows r_, r_^1 both live in this wave) -> no barrier
    float o0 = 0.f, o1 = 0.f, o2 = 0.f, o3 = 0.f;
    #pragma unroll 4
    for (int j = 0; j < KC; j += 4) {
        o0 = fmaf(ss[r_][j + 0], vs[j + 0][d_], o0);
        o1 = fmaf(ss[r_][j + 1], vs[j + 1][d_], o1);
        o2 = fmaf(ss[r_][j + 2], vs[j + 2][d_], o2);
        o3 = fmaf(ss[r_][j + 3], vs[j + 3][d_], o3);
    }
    float o = (o0 + o1) + (o2 + o3);
    int pidx = head * KSPLIT + kp;
    opart[((size_t)pidx * NN + i0 + r_) * DH + d_] = o;
    if (d_ == 0) {
        mpart[pidx * NN + i0 + r_] = m;
        lpart[pidx * NN + i0 + r_] = l;
    }
}

__global__ void k_attn_merge(const float* __restrict__ opart, const float* __restrict__ mpart,
        const float* __restrict__ lpart, float* __restrict__ attn_o) {
    int gid = blockIdx.x * 256 + threadIdx.x;   // 4*1024*32
    int d = gid & 31;
    int row = (gid >> 5) & 1023;
    int head = gid >> 15;
    float mv[KSPLIT];
    float M = -1e30f;
    #pragma unroll
    for (int p = 0; p < KSPLIT; ++p) {
        mv[p] = mpart[(head * KSPLIT + p) * NN + row];
        M = fmaxf(M, mv[p]);
    }
    float L = 0.f, o = 0.f;
    #pragma unroll
    for (int p = 0; p < KSPLIT; ++p) {
        float w = __expf(mv[p] - M);
        L = fmaf(lpart[(head * KSPLIT + p) * NN + row], w, L);
        o = fmaf(opart[((size_t)(head * KSPLIT + p) * NN + row) * DH + d], w, o);
    }
    attn_o[row * H + head * DH + d] = o / L;
}

// ---------------- pooling + head
__global__ void k_pool1(const float* __restrict__ h2, float* __restrict__ pp) {
    int b = blockIdx.x; // 0..31
    int t = threadIdx.x;
    int c = t & 127, rg = t >> 7;
    int r0 = b * 32 + rg * 16;
    float s = 0.f;
    #pragma unroll
    for (int r = 0; r < 16; ++r) s += h2[(r0 + r) * H + c];
    pp[(b * 2 + rg) * H + c] = s;
}

__global__ void k_pool2(const float* __restrict__ pp, const float* __restrict__ outW,
        const float* __restrict__ outB, float* __restrict__ out) {
    __shared__ float pooled[H];
    int t = threadIdx.x;
    float s = 0.f;
    #pragma unroll 8
    for (int p = 0; p < 64; ++p) s += pp[p * H + t];
    pooled[t] = s * (1.f / 1024.f);
    __syncthreads();
    if (t < 6) {
        float acc = outB[t];
        for (int c = 0; c < H; ++c) acc = fmaf(pooled[c], outW[c * 6 + t], acc);
        out[t] = (t == 1) ? fmaxf(acc, 0.f) : 1.f / (1.f + expf(-acc));
    }
}

extern "C" void kernel_launch(void* const* d_in, const int* in_sizes, int n_in,
                              void* d_out, int out_size, void* d_ws, size_t ws_size,
                              hipStream_t stream) {
    const float* x       = (const float*)d_in[0];
    const float* emb_W   = (const float*)d_in[1];
    const float* emb_b   = (const float*)d_in[2];
    const float* ln_g    = (const float*)d_in[3];
    const float* ln_b    = (const float*)d_in[4];
    const float* edge_W1 = (const float*)d_in[5];
    const float* edge_b1 = (const float*)d_in[6];
    const float* edge_W2 = (const float*)d_in[7];
    const float* edge_b2 = (const float*)d_in[8];
    const float* gc_W    = (const float*)d_in[9];
    const float* gc_b    = (const float*)d_in[10];
    const float* in_proj_W  = (const float*)d_in[11];
    const float* in_proj_b  = (const float*)d_in[12];
    const float* out_proj_W = (const float*)d_in[13];
    const float* out_proj_b = (const float*)d_in[14];
    const float* out_W   = (const float*)d_in[15];
    const float* out_b   = (const float*)d_in[16];
    float* out = (float*)d_out;

    float* ws = (float*)d_ws;
    float* aM      = ws;                  // 131072
    float* bM      = aM + NN * H;         // 131072
    float* adj     = bM + NN * H;         // 1048576
    float* g       = adj + NN * NN;       // 131072
    float* partial = g + NN * H;          // 524288
    float* qkv     = partial + 4 * NN * H;// 393216
    float* Wt_in   = qkv + NN * 384;      // 49152
    float* Wt_out  = Wt_in + 128 * 384;   // 16384
    float* pp      = Wt_out + 128 * 128;  // 8192
    // aliases (lifetimes disjoint):
    float* opart  = adj;            // after last spmm, adj is dead; exactly 1M floats
    float* mpart  = aM;             // after k_adj, aM/bM dead
    float* lpart  = aM + 32 * NN;
    float* attn_o = bM;
    float* h2     = g;              // after last spmm, g dead

    k_transpose<<<256, 256, 0, stream>>>(in_proj_W, out_proj_W, Wt_in, Wt_out);
    k_embed<<<NN, 128, 0, stream>>>(x, emb_W, emb_b, ln_g, ln_b, edge_W1, edge_b1,
                                    gc_W, aM, bM, g);
    k_adj<<<dim3(NN / AT, NN / AT), 256, 0, stream>>>(aM, bM, edge_W2, edge_b2, adj);

    for (int l = 0; l < NL; ++l) {
        k_spmm<<<dim3(NN / RT, 4), 256, 0, stream>>>(adj, g, partial);
        if (l < NL - 1)
            k_redmat128<<<NN, 128, 0, stream>>>(partial, gc_b + (size_t)l * H,
                                                gc_W + (size_t)(l + 1) * H * H, g);
        else
            k_redmat384<<<NN, 384, 0, stream>>>(partial, gc_b + (size_t)l * H,
                                                Wt_in, in_proj_b, qkv);
    }

    k_attn_part<<<dim3(NN / QR, HEADS, KSPLIT), 256, 0, stream>>>(qkv, opart, mpart, lpart);
    k_attn_merge<<<HEADS * NN * DH / 256, 256, 0, stream>>>(opart, mpart, lpart, attn_o);
    k_rowmat<<<NN, 128, H * sizeof(float), stream>>>(attn_o, Wt_out, out_proj_b, h2, H, 128);
    k_pool1<<<32, 256, 0, stream>>>(h2, pp);
    k_pool2<<<1, 128, 0, stream>>>(pp, out_W, out_b, out);
}

// Round 3
// 159.260 us; speedup vs baseline: 1.6535x; 1.0307x over previous
//
#include <hip/hip_runtime.h>
#include <math.h>

#define NN 1024
#define IN_DIM 64
#define H 128
#define NL 4
#define HEADS 4
#define DH 32
#define KSPLIT 8   // attention j-chunks of 128
#define NSPLIT 16  // spmm j-chunks of 64

// ---------------- embed: h=relu(LN(x@embW+b)); aM=h@W1a+eb1; bM=h@W1b; g0=h@gcW0
// also folds the in_proj/out_proj weight transposes (independent side work)
__global__ __launch_bounds__(128) void k_embed(const float* __restrict__ x,
        const float* __restrict__ embW, const float* __restrict__ embB,
        const float* __restrict__ lng, const float* __restrict__ lnb,
        const float* __restrict__ eW1, const float* __restrict__ eb1,
        const float* __restrict__ gcW0,
        const float* __restrict__ inW, const float* __restrict__ outW,
        float* __restrict__ Wt_in, float* __restrict__ Wt_out,
        float* __restrict__ aM, float* __restrict__ bM, float* __restrict__ g0) {
    __shared__ float xs[IN_DIM];
    __shared__ float hs[H];
    __shared__ float red[H];
    int i = blockIdx.x, t = threadIdx.x;
    // side work: weight transposes
    int gidx = i * 128 + t;
    if (gidx < 49152) {
        Wt_in[gidx] = inW[(gidx % 384) * 128 + gidx / 384];
    } else if (gidx < 65536) {
        int i2 = gidx - 49152;
        Wt_out[i2] = outW[(i2 % 128) * 128 + i2 / 128];
    }
    if (t < IN_DIM) xs[t] = x[i * IN_DIM + t];
    __syncthreads();
    float acc = embB[t];
    #pragma unroll 8
    for (int k = 0; k < IN_DIM; ++k) acc = fmaf(xs[k], embW[k * H + t], acc);
    red[t] = acc; __syncthreads();
    for (int s = 64; s > 0; s >>= 1) { if (t < s) red[t] += red[t + s]; __syncthreads(); }
    float mu = red[0] * (1.f / H);
    __syncthreads();
    float d = acc - mu;
    red[t] = d * d; __syncthreads();
    for (int s = 64; s > 0; s >>= 1) { if (t < s) red[t] += red[t + s]; __syncthreads(); }
    float var = red[0] * (1.f / H);
    float hv = d * rsqrtf(var + 1e-5f) * lng[t] + lnb[t];
    hv = fmaxf(hv, 0.f);
    hs[t] = hv;
    __syncthreads();
    float aa = eb1[t], bb = 0.f, gg = 0.f;
    #pragma unroll 8
    for (int k = 0; k < H; ++k) {
        float hk = hs[k];
        aa = fmaf(hk, eW1[k * H + t], aa);
        bb = fmaf(hk, eW1[(H + k) * H + t], bb);
        gg = fmaf(hk, gcW0[k * H + t], gg);
    }
    aM[i * H + t] = aa;
    bM[i * H + t] = bb;
    g0[i * H + t] = gg;
}

// ---------------- adj: 32x32 tile, b transposed in LDS, 4 outputs/thread via float4
#define AT 32
__global__ __launch_bounds__(256) void k_adj(const float* __restrict__ aM, const float* __restrict__ bM,
        const float* __restrict__ w2, const float* __restrict__ eb2p, float* __restrict__ adj) {
    __shared__ float as_[AT][H + 4];
    __shared__ float bst[H][AT + 4];
    __shared__ float w2s[H];
    int i0 = blockIdx.y * AT, j0 = blockIdx.x * AT;
    int t = threadIdx.x;
    for (int idx = t; idx < AT * H; idx += 256) {
        int r = idx >> 7, c = idx & 127;
        as_[r][c] = aM[(i0 + r) * H + c];
        bst[c][r] = bM[(j0 + r) * H + c];
    }
    if (t < H) w2s[t] = w2[t];
    __syncthreads();
    int ti = t >> 3, tjg = t & 7;
    float a0 = 0.f, a1 = 0.f, a2 = 0.f, a3 = 0.f;
    const float eb2 = eb2p[0];
    #pragma unroll 4
    for (int h = 0; h < H; ++h) {
        float av = as_[ti][h];
        float4 bv = *(const float4*)&bst[h][tjg * 4];
        float wh = w2s[h];
        a0 = fmaf(fmaxf(av + bv.x, 0.f), wh, a0);
        a1 = fmaf(fmaxf(av + bv.y, 0.f), wh, a1);
        a2 = fmaf(fmaxf(av + bv.z, 0.f), wh, a2);
        a3 = fmaf(fmaxf(av + bv.w, 0.f), wh, a3);
    }
    int i = i0 + ti, jb = j0 + tjg * 4;
    float4 ov;
    ov.x = (i == jb + 0) ? 0.f : 1.f / (1.f + __expf(-(a0 + eb2)));
    ov.y = (i == jb + 1) ? 0.f : 1.f / (1.f + __expf(-(a1 + eb2)));
    ov.z = (i == jb + 2) ? 0.f : 1.f / (1.f + __expf(-(a2 + eb2)));
    ov.w = (i == jb + 3) ? 0.f : 1.f / (1.f + __expf(-(a3 + eb2)));
    *(float4*)&adj[(size_t)i * NN + jb] = ov;
}

// ---------------- spmm: partial[p][i][c] = sum_{j in 64-chunk p} adj[i][j]*g[j][c]
// register-tiled 4x4: 16 FMA per (4 LDS broadcast b32 + 1 global b128)
__global__ __launch_bounds__(128) void k_spmm(const float* __restrict__ adj, const float* __restrict__ g,
        float* __restrict__ partial) {
    __shared__ float adjs[16][65];
    int r0 = blockIdx.x * 16;
    int j0 = blockIdx.y * 64;
    int t = threadIdx.x;
    #pragma unroll
    for (int it = 0; it < 2; ++it) {
        int idx = t + it * 128;
        int r = idx >> 4, jg = idx & 15;
        float4 av = *(const float4*)&adj[(size_t)(r0 + r) * NN + j0 + jg * 4];
        adjs[r][jg * 4 + 0] = av.x; adjs[r][jg * 4 + 1] = av.y;
        adjs[r][jg * 4 + 2] = av.z; adjs[r][jg * 4 + 3] = av.w;
    }
    __syncthreads();
    int rg = t >> 5, cg = t & 31;
    int c0 = cg * 4;
    float acc[4][4] = {};
    #pragma unroll 4
    for (int jj = 0; jj < 64; ++jj) {
        float ga[4];
        *(float4*)ga = *(const float4*)&g[(j0 + jj) * H + c0];
        #pragma unroll
        for (int r = 0; r < 4; ++r) {
            float av = adjs[rg * 4 + r][jj];
            #pragma unroll
            for (int c = 0; c < 4; ++c) acc[r][c] = fmaf(av, ga[c], acc[r][c]);
        }
    }
    #pragma unroll
    for (int r = 0; r < 4; ++r) {
        float4 ov = {acc[r][0], acc[r][1], acc[r][2], acc[r][3]};
        *(float4*)&partial[((size_t)blockIdx.y * NN + r0 + rg * 4 + r) * H + c0] = ov;
    }
}

// ---------------- fused 16-way reduce + bias + next matmul (H -> H)
__global__ __launch_bounds__(128) void k_redmat128(const float* __restrict__ partial,
        const float* __restrict__ bias, const float* __restrict__ W, float* __restrict__ outM) {
    __shared__ float s[H];
    int i = blockIdx.x, t = threadIdx.x;
    float v = bias[t];
    #pragma unroll
    for (int p = 0; p < NSPLIT; ++p) v += partial[(size_t)p * NN * H + i * H + t];
    s[t] = v;
    __syncthreads();
    float acc = 0.f;
    #pragma unroll 8
    for (int k = 0; k < H; ++k) acc = fmaf(s[k], W[k * H + t], acc);
    outM[i * H + t] = acc;
}

// ---------------- fused 16-way reduce + bias + qkv projection (H -> 384)
__global__ __launch_bounds__(384) void k_redmat384(const float* __restrict__ partial,
        const float* __restrict__ bias, const float* __restrict__ W,
        const float* __restrict__ bias2, float* __restrict__ outM) {
    __shared__ float s[H];
    int i = blockIdx.x, t = threadIdx.x;
    if (t < H) {
        float v = bias[t];
        #pragma unroll
        for (int p = 0; p < NSPLIT; ++p) v += partial[(size_t)p * NN * H + i * H + t];
        s[t] = v;
    }
    __syncthreads();
    float acc = bias2[t];
    #pragma unroll 8
    for (int k = 0; k < H; ++k) acc = fmaf(s[k], W[k * 384 + t], acc);
    outM[i * 384 + t] = acc;
}

// ---------------- split-K attention, register-tiled 4x4 QK and PV
__global__ __launch_bounds__(256) void k_attn_part(const float* __restrict__ qkv,
        float* __restrict__ opart, float* __restrict__ mpart, float* __restrict__ lpart) {
    __shared__ float kob[4][32][36];   // phase1: kT[32][132] (4608 fl); phase2: obuf[4][32][36]
    __shared__ float qT[32][36];
    __shared__ float pT[128][36];
    __shared__ float marr[32], larr[32];
    float* kT = &kob[0][0][0];
    const int t = threadIdx.x;
    const int head = blockIdx.y, kp = blockIdx.z;
    const int i0 = blockIdx.x * 32, j0 = kp * 128;
    const int qoff = head * DH, koff = H + head * DH, voff = 2 * H + head * DH;
    const float scale = 0.17677669529663687f; // 1/sqrt(32)
    {
        int qi = t >> 3, dg = t & 7;
        float4 qv = *(const float4*)&qkv[(i0 + qi) * 384 + qoff + dg * 4];
        qT[dg * 4 + 0][qi] = qv.x * scale;
        qT[dg * 4 + 1][qi] = qv.y * scale;
        qT[dg * 4 + 2][qi] = qv.z * scale;
        qT[dg * 4 + 3][qi] = qv.w * scale;
    }
    #pragma unroll
    for (int it = 0; it < 4; ++it) {
        int idx = t + it * 256;
        int j = idx >> 3, dg = idx & 7;
        float4 kv = *(const float4*)&qkv[(j0 + j) * 384 + koff + dg * 4];
        kT[(dg * 4 + 0) * 132 + j] = kv.x;
        kT[(dg * 4 + 1) * 132 + j] = kv.y;
        kT[(dg * 4 + 2) * 132 + j] = kv.z;
        kT[(dg * 4 + 3) * 132 + j] = kv.w;
    }
    __syncthreads();
    // ---- QK: thread (tq,tj) computes s[4q][4j]
    const int tq = t >> 5, tj = t & 31;
    float s[4][4] = {};
    #pragma unroll
    for (int kk = 0; kk < DH; ++kk) {
        float qa[4], ka[4];
        *(float4*)qa = *(float4*)&qT[kk][tq * 4];
        *(float4*)ka = *(float4*)&kT[kk * 132 + tj * 4];
        #pragma unroll
        for (int a = 0; a < 4; ++a)
            #pragma unroll
            for (int b = 0; b < 4; ++b) s[a][b] = fmaf(qa[a], ka[b], s[a][b]);
    }
    // ---- softmax over the 128-j chunk (reduce across tj lanes, width 32)
    #pragma unroll
    for (int a = 0; a < 4; ++a) {
        float mm = fmaxf(fmaxf(s[a][0], s[a][1]), fmaxf(s[a][2], s[a][3]));
        #pragma unroll
        for (int off = 16; off > 0; off >>= 1) mm = fmaxf(mm, __shfl_xor(mm, off));
        float ll = 0.f;
        #pragma unroll
        for (int b = 0; b < 4; ++b) { s[a][b] = __expf(s[a][b] - mm); ll += s[a][b]; }
        #pragma unroll
        for (int off = 16; off > 0; off >>= 1) ll += __shfl_xor(ll, off);
        if (tj == 0) { marr[tq * 4 + a] = mm; larr[tq * 4 + a] = ll; }
    }
    #pragma unroll
    for (int b = 0; b < 4; ++b)
        #pragma unroll
        for (int a = 0; a < 4; ++a) pT[tj * 4 + b][tq * 4 + a] = s[a][b];
    __syncthreads();
    // ---- PV: thread (qg,dg,st) computes o[4q][4d] over 32-j strip; V straight from L2
    const int qg = t >> 5, dg = (t >> 2) & 7, st = t & 3;
    float o[4][4] = {};
    #pragma unroll 4
    for (int jj = 0; jj < 32; ++jj) {
        int j = st * 32 + jj;
        float pa[4], va[4];
        *(float4*)pa = *(float4*)&pT[j][qg * 4];
        *(float4*)va = *(const float4*)&qkv[(j0 + j) * 384 + voff + dg * 4];
        #pragma unroll
        for (int a = 0; a < 4; ++a)
            #pragma unroll
            for (int b = 0; b < 4; ++b) o[a][b] = fmaf(pa[a], va[b], o[a][b]);
    }
    #pragma unroll
    for (int a = 0; a < 4; ++a)
        #pragma unroll
        for (int b = 0; b < 4; ++b) kob[st][qg * 4 + a][dg * 4 + b] = o[a][b];
    __syncthreads();
    // ---- strip reduce + store
    {
        int q = t >> 3, d0 = (t & 7) * 4;
        float r0[4], r1[4], r2[4], r3[4];
        *(float4*)r0 = *(float4*)&kob[0][q][d0];
        *(float4*)r1 = *(float4*)&kob[1][q][d0];
        *(float4*)r2 = *(float4*)&kob[2][q][d0];
        *(float4*)r3 = *(float4*)&kob[3][q][d0];
        float4 ov;
        ov.x = (r0[0] + r1[0]) + (r2[0] + r3[0]);
        ov.y = (r0[1] + r1[1]) + (r2[1] + r3[1]);
        ov.z = (r0[2] + r1[2]) + (r2[2] + r3[2]);
        ov.w = (r0[3] + r1[3]) + (r2[3] + r3[3]);
        int pidx = head * KSPLIT + kp;
        *(float4*)&opart[((size_t)pidx * NN + i0 + q) * DH + d0] = ov;
        if (t < 32) {
            mpart[pidx * NN + i0 + t] = marr[t];
            lpart[pidx * NN + i0 + t] = larr[t];
        }
    }
}

// ---------------- fused attention merge + out_proj
__global__ __launch_bounds__(128) void k_mergeproj(const float* __restrict__ opart,
        const float* __restrict__ mpart, const float* __restrict__ lpart,
        const float* __restrict__ Wt_out, const float* __restrict__ bias,
        float* __restrict__ h2) {
    __shared__ float s[H];
    int row = blockIdx.x, t = threadIdx.x;
    int head = t >> 5, d = t & 31;
    float mv[KSPLIT];
    float M = -1e30f;
    #pragma unroll
    for (int p = 0; p < KSPLIT; ++p) {
        mv[p] = mpart[(head * KSPLIT + p) * NN + row];
        M = fmaxf(M, mv[p]);
    }
    float L = 0.f, o = 0.f;
    #pragma unroll
    for (int p = 0; p < KSPLIT; ++p) {
        float w = __expf(mv[p] - M);
        L = fmaf(lpart[(head * KSPLIT + p) * NN + row], w, L);
        o = fmaf(opart[((size_t)(head * KSPLIT + p) * NN + row) * DH + d], w, o);
    }
    s[t] = o / L;
    __syncthreads();
    float acc = bias[t];
    #pragma unroll 8
    for (int k = 0; k < H; ++k) acc = fmaf(s[k], Wt_out[k * H + t], acc);
    h2[row * H + t] = acc;
}

// ---------------- pooling + head
__global__ void k_pool1(const float* __restrict__ h2, float* __restrict__ pp) {
    int b = blockIdx.x; // 0..31
    int t = threadIdx.x;
    int c = t & 127, rg = t >> 7;
    int r0 = b * 32 + rg * 16;
    float s = 0.f;
    #pragma unroll
    for (int r = 0; r < 16; ++r) s += h2[(r0 + r) * H + c];
    pp[(b * 2 + rg) * H + c] = s;
}

__global__ void k_pool2(const float* __restrict__ pp, const float* __restrict__ outW,
        const float* __restrict__ outB, float* __restrict__ out) {
    __shared__ float pooled[H];
    int t = threadIdx.x;
    float s = 0.f;
    #pragma unroll 8
    for (int p = 0; p < 64; ++p) s += pp[p * H + t];
    pooled[t] = s * (1.f / 1024.f);
    __syncthreads();
    if (t < 6) {
        float acc = outB[t];
        for (int c = 0; c < H; ++c) acc = fmaf(pooled[c], outW[c * 6 + t], acc);
        out[t] = (t == 1) ? fmaxf(acc, 0.f) : 1.f / (1.f + expf(-acc));
    }
}

extern "C" void kernel_launch(void* const* d_in, const int* in_sizes, int n_in,
                              void* d_out, int out_size, void* d_ws, size_t ws_size,
                              hipStream_t stream) {
    const float* x       = (const float*)d_in[0];
    const float* emb_W   = (const float*)d_in[1];
    const float* emb_b   = (const float*)d_in[2];
    const float* ln_g    = (const float*)d_in[3];
    const float* ln_b    = (const float*)d_in[4];
    const float* edge_W1 = (const float*)d_in[5];
    const float* edge_b1 = (const float*)d_in[6];
    const float* edge_W2 = (const float*)d_in[7];
    const float* edge_b2 = (const float*)d_in[8];
    const float* gc_W    = (const float*)d_in[9];
    const float* gc_b    = (const float*)d_in[10];
    const float* in_proj_W  = (const float*)d_in[11];
    const float* in_proj_b  = (const float*)d_in[12];
    const float* out_proj_W = (const float*)d_in[13];
    const float* out_proj_b = (const float*)d_in[14];
    const float* out_W   = (const float*)d_in[15];
    const float* out_b   = (const float*)d_in[16];
    float* out = (float*)d_out;

    float* ws = (float*)d_ws;
    float* aM      = ws;                    // 131072
    float* bM      = aM + NN * H;           // 131072
    float* adj     = bM + NN * H;           // 1048576
    float* g       = adj + NN * NN;         // 131072
    float* partial = g + NN * H;            // 16*131072 = 2097152
    float* qkv     = partial + (size_t)NSPLIT * NN * H;  // 393216
    float* Wt_in   = qkv + NN * 384;        // 49152
    float* Wt_out  = Wt_in + 128 * 384;     // 16384
    float* pp      = Wt_out + 128 * 128;    // 8192
    // aliases (lifetimes disjoint):
    float* opart = adj;          // 32*1024*32 = 1048576, adj dead after last spmm
    float* mpart = aM;           // 32768, aM dead after k_adj
    float* lpart = aM + 32 * NN; // 32768
    float* h2    = g;            // g dead after last redmat384

    k_embed<<<NN, 128, 0, stream>>>(x, emb_W, emb_b, ln_g, ln_b, edge_W1, edge_b1,
                                    gc_W, in_proj_W, out_proj_W, Wt_in, Wt_out,
                                    aM, bM, g);
    k_adj<<<dim3(NN / AT, NN / AT), 256, 0, stream>>>(aM, bM, edge_W2, edge_b2, adj);

    for (int l = 0; l < NL; ++l) {
        k_spmm<<<dim3(NN / 16, NSPLIT), 128, 0, stream>>>(adj, g, partial);
        if (l < NL - 1)
            k_redmat128<<<NN, 128, 0, stream>>>(partial, gc_b + (size_t)l * H,
                                                gc_W + (size_t)(l + 1) * H * H, g);
        else
            k_redmat384<<<NN, 384, 0, stream>>>(partial, gc_b + (size_t)l * H,
                                                Wt_in, in_proj_b, qkv);
    }

    k_attn_part<<<dim3(NN / 32, HEADS, KSPLIT), 256, 0, stream>>>(qkv, opart, mpart, lpart);
    k_mergeproj<<<NN, 128, 0, stream>>>(opart, mpart, lpart, Wt_out, out_proj_b, h2);
    k_pool1<<<32, 256, 0, stream>>>(h2, pp);
    k_pool2<<<1, 128, 0, stream>>>(pp, out_W, out_b, out);
}